// Round 8
// baseline (236.964 us; speedup 1.0000x reference)
//
#include <hip/hip_runtime.h>
#include <hip/hip_bf16.h>
#include <stdint.h>

#define NTOK 8192
#define DIM  512
#define QKVW 1536

typedef __attribute__((ext_vector_type(8))) short bf16x8;
typedef __attribute__((ext_vector_type(4))) float f32x4;

static __device__ __forceinline__ unsigned short f2b(float f) {
    union { float f; unsigned int u; } v; v.f = f;
    unsigned int r = v.u + 0x7fffu + ((v.u >> 16) & 1u);
    return (unsigned short)(r >> 16);
}

static __device__ __forceinline__ void gld_lds16(const void* g, void* l) {
    __builtin_amdgcn_global_load_lds(
        (__attribute__((address_space(1))) void*)(uintptr_t)g,
        (__attribute__((address_space(3))) void*)(uintptr_t)l,
        16, 0, 0);
}

#define SBAR() do { __builtin_amdgcn_sched_barrier(0); __builtin_amdgcn_s_barrier(); __builtin_amdgcn_sched_barrier(0); } while (0)

template <int N> static __device__ __forceinline__ void vmw() {
    __builtin_amdgcn_sched_barrier(0);
    if constexpr (N == 4)      asm volatile("s_waitcnt vmcnt(4)" ::: "memory");
    else                       asm volatile("s_waitcnt vmcnt(0)" ::: "memory");
    __builtin_amdgcn_sched_barrier(0);
}

// ---------------- converts ----------------

__global__ void f2b_kernel(const float* __restrict__ src, unsigned short* __restrict__ dst, int n4) {
    int i = blockIdx.x * blockDim.x + threadIdx.x;
    if (i < n4) {
        float4 f = ((const float4*)src)[i];
        ushort4 o;
        o.x = f2b(f.x); o.y = f2b(f.y); o.z = f2b(f.z); o.w = f2b(f.w);
        ((ushort4*)dst)[i] = o;
    }
}

__global__ void bias_concat(const float* __restrict__ bq, const float* __restrict__ bk,
                            const float* __restrict__ bv, float* __restrict__ bc) {
    int i = blockIdx.x * blockDim.x + threadIdx.x;
    if (i < 512)       bc[i] = bq[i];
    else if (i < 1024) bc[i] = bk[i - 512];
    else if (i < 1536) bc[i] = bv[i - 1024];
}

// ---------------- V transpose ----------------
__global__ void transpose_v(const unsigned short* __restrict__ qkv, unsigned short* __restrict__ vt) {
    __shared__ unsigned short t[64][65];
    int j0 = blockIdx.x * 64;
    int d0 = blockIdx.y * 64;
    int tid = threadIdx.x;
    int c  = tid & 63;
    int r4 = tid >> 6;
    #pragma unroll
    for (int r = r4; r < 64; r += 4)
        t[r][c] = qkv[(size_t)(j0 + r) * QKVW + 1024 + d0 + c];
    __syncthreads();
    #pragma unroll
    for (int r = r4; r < 64; r += 4)
        vt[(size_t)(d0 + r) * NTOK + j0 + c] = t[c][r];
}

// ---------------- 128x128 ring-3 GEMM, C = A * B^T ----------------
// Staging chunk c = w*128 + {l, 64+l}: LDS byte c*16 (linear dest), row = c>>2,
// slot s = c&3, global source quarter p = s ^ ((row>>1)&3)  -> coalesced
// (4 lanes/row = full 64B line) AND conflict-free ds_read_b128 on readback.
// Ring-3 pipeline (T4): at iter t stage tile t+2 into buf (t+2)%3; after
// MFMA(t) wait vmcnt(4) only (newest tile's 4 loads stay in flight across
// the barrier). 48KB LDS -> 3 blocks/CU.
// EPI 0: bf16 store + bias[col]            (QKV projection)
// EPI 1: bf16 store + atomic row sum-sq    (S = Q K^T)
// EPI 2: fp32 partial store (split-K by z) (O = S V)
template <int EPI, int CH>
__global__ __launch_bounds__(256, 3) void gemmx(
    const unsigned short* __restrict__ A, int lda,
    const unsigned short* __restrict__ B, int ldb,
    int Ksplit,
    void* __restrict__ Cout, int ldc,
    const float* __restrict__ bias,
    float* __restrict__ rowss) {

    __shared__ __align__(16) char lds[49152];

    const int t = threadIdx.x;
    const int l = t & 63, w = t >> 6;
    const int wr = w >> 1, wc = w & 1;

    // XCD-chunked swizzle (gridDim.y % 8 == 0, gridDim.x % CH == 0)
    const int gx = gridDim.x;
    const int nbm = gridDim.y >> 3;
    const int bid = blockIdx.y * gx + blockIdx.x;
    const int xcd = bid & 7, qq = bid >> 3;
    const int win = nbm * CH;
    const int grp = qq / win, rr = qq % win;
    const int bm = xcd * nbm + rr / CH;
    const int bn = grp * CH + rr % CH;

    const int kt0 = blockIdx.z * Ksplit;
    const int NT = Ksplit >> 5;

    // coalesced staging pointers, source quarter = (c&3) ^ ((c>>3)&3)
    const int c0 = w * 128 + l;
    const int c1 = c0 + 64;
    const int r0 = c0 >> 2, r1 = c1 >> 2;
    const int col0 = (((c0 & 3) ^ ((c0 >> 3) & 3)) << 3);
    const int col1 = (((c1 & 3) ^ ((c1 >> 3) & 3)) << 3);
    const unsigned short* gA0 = A + (size_t)(bm * 128 + r0) * lda + kt0 + col0;
    const unsigned short* gA1 = A + (size_t)(bm * 128 + r1) * lda + kt0 + col1;
    const unsigned short* gB0 = B + (size_t)(bn * 128 + r0) * ldb + kt0 + col0;
    const unsigned short* gB1 = B + (size_t)(bn * 128 + r1) * ldb + kt0 + col1;

    auto STAGE = [&](int buf, int tt) {
        char* d = lds + buf * 16384 + w * 2048;
        const int o = tt * 32;
        gld_lds16(gA0 + o, d);
        gld_lds16(gA1 + o, d + 1024);
        gld_lds16(gB0 + o, d + 8192);
        gld_lds16(gB1 + o, d + 8192 + 1024);
    };

    f32x4 acc[4][4] = {};

    // frag-read byte offsets: slot = Q ^ ((lr>>1)&3)
    const int lr = l & 15, Q = l >> 4;
    const int sw = ((Q ^ ((lr >> 1) & 3)) << 4);
    const int lrA = (wr * 64 + lr) * 64 + sw;
    const int lrB = 8192 + (wc * 64 + lr) * 64 + sw;

    // prologue: fill buffers 0,1 with tiles 0,1
    STAGE(0, 0);
    STAGE(1, 1);
    vmw<4>();          // tile 0 landed (tile 1's 4 loads may be in flight)
    SBAR();

    int br = 0, bs = 2;
    for (int tt = 0; tt < NT; ++tt) {
        const bool st = (tt + 2 < NT);
        if (st) STAGE(bs, tt + 2);          // lookahead-2 stage FIRST
        __builtin_amdgcn_sched_barrier(0);

        const char* lb = lds + br * 16384;
        bf16x8 af[4], bf[4];
        #pragma unroll
        for (int m = 0; m < 4; ++m) af[m] = *(const bf16x8*)(lb + lrA + m * 1024);
        #pragma unroll
        for (int n = 0; n < 4; ++n) bf[n] = *(const bf16x8*)(lb + lrB + n * 1024);

        #pragma unroll
        for (int m = 0; m < 4; ++m)
            #pragma unroll
            for (int n = 0; n < 4; ++n)
                acc[m][n] = __builtin_amdgcn_mfma_f32_16x16x32_bf16(af[m], bf[n], acc[m][n], 0, 0, 0);

        if (tt + 1 < NT) {
            if (st) vmw<4>();   // tile tt+1 landed; tile tt+2's 4 loads stay in flight
            else    vmw<0>();   // draining epilogue
            SBAR();
            br = (br == 2) ? 0 : br + 1;
            bs = (bs == 2) ? 0 : bs + 1;
        }
    }

    const int rbase = bm * 128 + wr * 64;
    const int cbase = bn * 128 + wc * 64;
    const int g4 = Q * 4;
    const int lc = lr;

    if constexpr (EPI == 0) {
        unsigned short* C = (unsigned short*)Cout;
        #pragma unroll
        for (int m = 0; m < 4; ++m)
            #pragma unroll
            for (int n = 0; n < 4; ++n)
                #pragma unroll
                for (int j = 0; j < 4; ++j) {
                    int rrow = rbase + m * 16 + g4 + j;
                    int ccol = cbase + n * 16 + lc;
                    C[(size_t)rrow * ldc + ccol] = f2b(acc[m][n][j] + bias[ccol]);
                }
    } else if constexpr (EPI == 1) {
        unsigned short* C = (unsigned short*)Cout;
        #pragma unroll
        for (int m = 0; m < 4; ++m)
            #pragma unroll
            for (int n = 0; n < 4; ++n)
                #pragma unroll
                for (int j = 0; j < 4; ++j) {
                    int rrow = rbase + m * 16 + g4 + j;
                    int ccol = cbase + n * 16 + lc;
                    C[(size_t)rrow * ldc + ccol] = f2b(acc[m][n][j]);
                }
        #pragma unroll
        for (int m = 0; m < 4; ++m)
            #pragma unroll
            for (int j = 0; j < 4; ++j) {
                float p = 0.f;
                #pragma unroll
                for (int n = 0; n < 4; ++n) {
                    float v = acc[m][n][j];
                    p += v * v;
                }
                p += __shfl_xor(p, 1);
                p += __shfl_xor(p, 2);
                p += __shfl_xor(p, 4);
                p += __shfl_xor(p, 8);
                if ((l & 15) == 0)
                    atomicAdd(&rowss[rbase + m * 16 + g4 + j], p);
            }
    } else {
        float* C = (float*)Cout + (size_t)blockIdx.z * NTOK * ldc;
        #pragma unroll
        for (int m = 0; m < 4; ++m)
            #pragma unroll
            for (int n = 0; n < 4; ++n)
                #pragma unroll
                for (int j = 0; j < 4; ++j) {
                    int rrow = rbase + m * 16 + g4 + j;
                    int ccol = cbase + n * 16 + lc;
                    C[(size_t)rrow * ldc + ccol] = acc[m][n][j];
                }
    }
}

// ---------------- split-K reduce + row-norm scale ----------------
__global__ void reduce_scale(const float* __restrict__ p, const float* __restrict__ rss,
                             float* __restrict__ out) {
    int i = blockIdx.x * blockDim.x + threadIdx.x;  // over NTOK*DIM/4
    const size_t stride = (size_t)NTOK * DIM / 4;
    const float4 a = ((const float4*)p)[i];
    const float4 b = ((const float4*)p)[i + stride];
    int r = i >> 7;  // (i*4)/DIM
    float s = 1.0f / fmaxf(sqrtf(rss[r]), 1e-12f);
    float4 o;
    o.x = (a.x + b.x) * s;
    o.y = (a.y + b.y) * s;
    o.z = (a.z + b.z) * s;
    o.w = (a.w + b.w) * s;
    ((float4*)out)[i] = o;
}

extern "C" void kernel_launch(void* const* d_in, const int* in_sizes, int n_in,
                              void* d_out, int out_size, void* d_ws, size_t ws_size,
                              hipStream_t stream) {
    const float* x  = (const float*)d_in[0];
    const float* Wq = (const float*)d_in[1];
    const float* bq = (const float*)d_in[2];
    const float* Wk = (const float*)d_in[3];
    const float* bk = (const float*)d_in[4];
    const float* Wv = (const float*)d_in[5];
    const float* bv = (const float*)d_in[6];
    float* out = (float*)d_out;

    char* ws = (char*)d_ws;
    size_t off = 0;
    auto alloc = [&](size_t bytes) -> void* {
        void* p = ws + off;
        off = (off + bytes + 255) & ~(size_t)255;
        return p;
    };

    unsigned short* xb   = (unsigned short*)alloc((size_t)NTOK * DIM * 2);
    unsigned short* Wb   = (unsigned short*)alloc((size_t)QKVW * DIM * 2);
    float*          bc   = (float*)alloc(QKVW * 4);
    unsigned short* QKV  = (unsigned short*)alloc((size_t)NTOK * QKVW * 2);
    unsigned short* Vt   = (unsigned short*)alloc((size_t)DIM * NTOK * 2);
    float*          rss  = (float*)alloc(NTOK * 4);
    float*          part = (float*)alloc((size_t)2 * NTOK * DIM * 4);
    unsigned short* S    = (unsigned short*)alloc((size_t)NTOK * NTOK * 2);

    // converts
    f2b_kernel<<<(NTOK * DIM / 4 + 255) / 256, 256, 0, stream>>>(x, xb, NTOK * DIM / 4);
    f2b_kernel<<<(DIM * DIM / 4 + 255) / 256, 256, 0, stream>>>(Wq, Wb, DIM * DIM / 4);
    f2b_kernel<<<(DIM * DIM / 4 + 255) / 256, 256, 0, stream>>>(Wk, Wb + DIM * DIM, DIM * DIM / 4);
    f2b_kernel<<<(DIM * DIM / 4 + 255) / 256, 256, 0, stream>>>(Wv, Wb + 2 * DIM * DIM, DIM * DIM / 4);
    bias_concat<<<6, 256, 0, stream>>>(bq, bk, bv, bc);
    hipMemsetAsync(rss, 0, NTOK * 4, stream);

    // QKV = x @ Wb^T + bias   [8192 x 1536], K=512   (grid 12x64, CH=12)
    gemmx<0, 12><<<dim3(QKVW / 128, NTOK / 128), 256, 0, stream>>>(
        xb, DIM, Wb, DIM, DIM, QKV, QKVW, bc, nullptr);

    // Vt[d][j] from QKV's V block
    transpose_v<<<dim3(NTOK / 64, DIM / 64), 256, 0, stream>>>(QKV, Vt);

    // S = Q @ K^T  [8192 x 8192], K=512 ; rowss += per-row sumsq  (grid 64x64, CH=16)
    gemmx<1, 16><<<dim3(NTOK / 128, NTOK / 128), 256, 0, stream>>>(
        QKV, QKVW, QKV + DIM, QKVW, DIM, S, NTOK, nullptr, rss);

    // O partials = S @ Vt^T, split-K=2  [8192 x 512]  (grid 4x64x2, CH=4)
    gemmx<2, 4><<<dim3(DIM / 128, NTOK / 128, 2), 256, 0, stream>>>(
        S, NTOK, Vt, NTOK, NTOK / 2, part, DIM, nullptr, nullptr);

    // out = (p0+p1) * rsqrt(rowss)
    reduce_scale<<<NTOK * DIM / 4 / 256, 256, 0, stream>>>(part, rss, out);
}

// Round 9
// 224.041 us; speedup vs baseline: 1.0577x; 1.0577x over previous
//
#include <hip/hip_runtime.h>
#include <hip/hip_bf16.h>
#include <stdint.h>

#define NTOK 8192
#define DIM  512
#define QKVW 1536

typedef __attribute__((ext_vector_type(8))) short bf16x8;
typedef __attribute__((ext_vector_type(4))) float f32x4;

static __device__ __forceinline__ unsigned short f2b(float f) {
    union { float f; unsigned int u; } v; v.f = f;
    unsigned int r = v.u + 0x7fffu + ((v.u >> 16) & 1u);
    return (unsigned short)(r >> 16);
}

static __device__ __forceinline__ void gld_lds16(const void* g, void* l) {
    __builtin_amdgcn_global_load_lds(
        (__attribute__((address_space(1))) void*)(uintptr_t)g,
        (__attribute__((address_space(3))) void*)(uintptr_t)l,
        16, 0, 0);
}

#define SBAR() do { __builtin_amdgcn_sched_barrier(0); __builtin_amdgcn_s_barrier(); __builtin_amdgcn_sched_barrier(0); } while (0)
#define VMW0() do { __builtin_amdgcn_sched_barrier(0); asm volatile("s_waitcnt vmcnt(0)" ::: "memory"); __builtin_amdgcn_sched_barrier(0); } while (0)

// ---------------- converts ----------------

__global__ void f2b_kernel(const float* __restrict__ src, unsigned short* __restrict__ dst, int n4) {
    int i = blockIdx.x * blockDim.x + threadIdx.x;
    if (i < n4) {
        float4 f = ((const float4*)src)[i];
        ushort4 o;
        o.x = f2b(f.x); o.y = f2b(f.y); o.z = f2b(f.z); o.w = f2b(f.w);
        ((ushort4*)dst)[i] = o;
    }
}

__global__ void bias_concat(const float* __restrict__ bq, const float* __restrict__ bk,
                            const float* __restrict__ bv, float* __restrict__ bc) {
    int i = blockIdx.x * blockDim.x + threadIdx.x;
    if (i < 512)       bc[i] = bq[i];
    else if (i < 1024) bc[i] = bk[i - 512];
    else if (i < 1536) bc[i] = bv[i - 1024];
}

// ---------------- V transpose ----------------
__global__ void transpose_v(const unsigned short* __restrict__ qkv, unsigned short* __restrict__ vt) {
    __shared__ unsigned short t[64][65];
    int j0 = blockIdx.x * 64;
    int d0 = blockIdx.y * 64;
    int tid = threadIdx.x;
    int c  = tid & 63;
    int r4 = tid >> 6;
    #pragma unroll
    for (int r = r4; r < 64; r += 4)
        t[r][c] = qkv[(size_t)(j0 + r) * QKVW + 1024 + d0 + c];
    __syncthreads();
    #pragma unroll
    for (int r = r4; r < 64; r += 4)
        vt[(size_t)(d0 + r) * NTOK + j0 + c] = t[c][r];
}

// ---------------- 128x256 double-buffered GEMM, C = A * B^T ----------------
// 4 waves (2wr x 2wc), wave-tile 64x128, acc[4][8] (FLOP/LDS-byte = 42.7
// vs 32 at 64x64 -> LDS pipe no longer binds vs MFMA pipe).
// Staging chunk c = issue*256 + t: LDS byte c*16 (linear dest), row = c>>2,
// slot s = c&3, source quarter p = s ^ ((row>>1)&3) -> coalesced full-64B-line
// fetches AND conflict-free ds_read_b128 on readback (verified 0-conflict r7/r8).
// Double buffer 2 x 24KB; STAGE(t+1) before compute(t); one vmcnt(0)+s_barrier
// per K-tile. ~210 VGPR -> 8 waves/CU = 2 blocks/CU.
// EPI 0: bf16 store + bias[col]            (QKV projection)
// EPI 1: bf16 store + atomic row sum-sq    (S = Q K^T)
// EPI 2: fp32 partial store (split-K by z) (O = S V)
template <int EPI, int CH>
__global__ __launch_bounds__(256, 2) void gemmx(
    const unsigned short* __restrict__ A, int lda,
    const unsigned short* __restrict__ B, int ldb,
    int Ksplit,
    void* __restrict__ Cout, int ldc,
    const float* __restrict__ bias,
    float* __restrict__ rowss) {

    __shared__ __align__(16) char lds[49152];   // 2 x (A 8KB | B 16KB)

    const int t = threadIdx.x;
    const int l = t & 63, w = t >> 6;
    const int wr = w >> 1, wc = w & 1;

    // XCD-chunked swizzle (gridDim.y % 8 == 0, gridDim.x % CH == 0)
    const int gx = gridDim.x;
    const int nbm = gridDim.y >> 3;
    const int bid = blockIdx.y * gx + blockIdx.x;
    const int xcd = bid & 7, qq = bid >> 3;
    const int win = nbm * CH;
    const int grp = qq / win, rr = qq % win;
    const int bm = xcd * nbm + rr / CH;
    const int bn = grp * CH + rr % CH;

    const int kt0 = blockIdx.z * Ksplit;
    const int NT = Ksplit >> 5;

    // staging source pointers: issue i covers chunks [i*256, i*256+256)
    const unsigned short* srcA0;
    const unsigned short* srcA1;
    const unsigned short* srcB0;
    const unsigned short* srcB1;
    const unsigned short* srcB2;
    const unsigned short* srcB3;
    {
        int c, row, p;
        c = t;         row = c >> 2; p = (c & 3) ^ ((c >> 3) & 3);
        srcA0 = A + (size_t)(bm * 128 + row) * lda + kt0 + p * 8;
        c = 256 + t;   row = c >> 2; p = (c & 3) ^ ((c >> 3) & 3);
        srcA1 = A + (size_t)(bm * 128 + row) * lda + kt0 + p * 8;
        c = t;         row = c >> 2; p = (c & 3) ^ ((c >> 3) & 3);
        srcB0 = B + (size_t)(bn * 256 + row) * ldb + kt0 + p * 8;
        c = 256 + t;   row = c >> 2; p = (c & 3) ^ ((c >> 3) & 3);
        srcB1 = B + (size_t)(bn * 256 + row) * ldb + kt0 + p * 8;
        c = 512 + t;   row = c >> 2; p = (c & 3) ^ ((c >> 3) & 3);
        srcB2 = B + (size_t)(bn * 256 + row) * ldb + kt0 + p * 8;
        c = 768 + t;   row = c >> 2; p = (c & 3) ^ ((c >> 3) & 3);
        srcB3 = B + (size_t)(bn * 256 + row) * ldb + kt0 + p * 8;
    }

    auto STAGE = [&](int buf, int tt) {
        char* d = lds + buf * 24576 + w * 1024;   // wave-uniform base
        const int o = tt * 32;
        gld_lds16(srcA0 + o, d);
        gld_lds16(srcA1 + o, d + 4096);
        gld_lds16(srcB0 + o, d + 8192);
        gld_lds16(srcB1 + o, d + 12288);
        gld_lds16(srcB2 + o, d + 16384);
        gld_lds16(srcB3 + o, d + 20480);
    };

    f32x4 acc[4][8] = {};

    // frag-read byte offsets: slot = Q ^ ((lr>>1)&3)
    const int lr = l & 15, Q = l >> 4;
    const int sw = ((Q ^ ((lr >> 1) & 3)) << 4);
    const int lrA = (wr * 64 + lr) * 64 + sw;
    const int lrB = 8192 + (wc * 128 + lr) * 64 + sw;

    STAGE(0, 0);
    VMW0();
    SBAR();

    int cur = 0;
    for (int tt = 0; tt < NT; ++tt) {
        const bool more = (tt + 1 < NT);
        if (more) STAGE(cur ^ 1, tt + 1);   // issue next-tile loads FIRST
        __builtin_amdgcn_sched_barrier(0);

        const char* lb = lds + cur * 24576;
        bf16x8 af[4], bf[8];
        #pragma unroll
        for (int m = 0; m < 4; ++m) af[m] = *(const bf16x8*)(lb + lrA + m * 1024);
        #pragma unroll
        for (int n = 0; n < 8; ++n) bf[n] = *(const bf16x8*)(lb + lrB + n * 1024);

        #pragma unroll
        for (int m = 0; m < 4; ++m)
            #pragma unroll
            for (int n = 0; n < 8; ++n)
                acc[m][n] = __builtin_amdgcn_mfma_f32_16x16x32_bf16(af[m], bf[n], acc[m][n], 0, 0, 0);

        if (more) {
            VMW0();        // next buffer landed
            SBAR();        // all waves done reading cur
            cur ^= 1;
        }
    }

    const int rbase = bm * 128 + wr * 64;
    const int cbase = bn * 256 + wc * 128;
    const int g4 = Q * 4;

    if constexpr (EPI == 0) {
        unsigned short* C = (unsigned short*)Cout;
        #pragma unroll
        for (int m = 0; m < 4; ++m)
            #pragma unroll
            for (int n = 0; n < 8; ++n)
                #pragma unroll
                for (int j = 0; j < 4; ++j) {
                    int rrow = rbase + m * 16 + g4 + j;
                    int ccol = cbase + n * 16 + lr;
                    C[(size_t)rrow * ldc + ccol] = f2b(acc[m][n][j] + bias[ccol]);
                }
    } else if constexpr (EPI == 1) {
        unsigned short* C = (unsigned short*)Cout;
        #pragma unroll
        for (int m = 0; m < 4; ++m)
            #pragma unroll
            for (int n = 0; n < 8; ++n)
                #pragma unroll
                for (int j = 0; j < 4; ++j) {
                    int rrow = rbase + m * 16 + g4 + j;
                    int ccol = cbase + n * 16 + lr;
                    C[(size_t)rrow * ldc + ccol] = f2b(acc[m][n][j]);
                }
        #pragma unroll
        for (int m = 0; m < 4; ++m)
            #pragma unroll
            for (int j = 0; j < 4; ++j) {
                float p = 0.f;
                #pragma unroll
                for (int n = 0; n < 8; ++n) {
                    float v = acc[m][n][j];
                    p += v * v;
                }
                p += __shfl_xor(p, 1);
                p += __shfl_xor(p, 2);
                p += __shfl_xor(p, 4);
                p += __shfl_xor(p, 8);
                if ((l & 15) == 0)
                    atomicAdd(&rowss[rbase + m * 16 + g4 + j], p);
            }
    } else {
        float* C = (float*)Cout + (size_t)blockIdx.z * NTOK * ldc;
        #pragma unroll
        for (int m = 0; m < 4; ++m)
            #pragma unroll
            for (int n = 0; n < 8; ++n)
                #pragma unroll
                for (int j = 0; j < 4; ++j) {
                    int rrow = rbase + m * 16 + g4 + j;
                    int ccol = cbase + n * 16 + lr;
                    C[(size_t)rrow * ldc + ccol] = acc[m][n][j];
                }
    }
}

// ---------------- split-K reduce + row-norm scale ----------------
__global__ void reduce_scale(const float* __restrict__ p, const float* __restrict__ rss,
                             float* __restrict__ out) {
    int i = blockIdx.x * blockDim.x + threadIdx.x;  // over NTOK*DIM/4
    const size_t stride = (size_t)NTOK * DIM / 4;
    const float4 a = ((const float4*)p)[i];
    const float4 b = ((const float4*)p)[i + stride];
    const float4 c = ((const float4*)p)[i + 2 * stride];
    const float4 d = ((const float4*)p)[i + 3 * stride];
    int r = i >> 7;  // (i*4)/DIM
    float s = 1.0f / fmaxf(sqrtf(rss[r]), 1e-12f);
    float4 o;
    o.x = (a.x + b.x + c.x + d.x) * s;
    o.y = (a.y + b.y + c.y + d.y) * s;
    o.z = (a.z + b.z + c.z + d.z) * s;
    o.w = (a.w + b.w + c.w + d.w) * s;
    ((float4*)out)[i] = o;
}

extern "C" void kernel_launch(void* const* d_in, const int* in_sizes, int n_in,
                              void* d_out, int out_size, void* d_ws, size_t ws_size,
                              hipStream_t stream) {
    const float* x  = (const float*)d_in[0];
    const float* Wq = (const float*)d_in[1];
    const float* bq = (const float*)d_in[2];
    const float* Wk = (const float*)d_in[3];
    const float* bk = (const float*)d_in[4];
    const float* Wv = (const float*)d_in[5];
    const float* bv = (const float*)d_in[6];
    float* out = (float*)d_out;

    char* ws = (char*)d_ws;
    size_t off = 0;
    auto alloc = [&](size_t bytes) -> void* {
        void* p = ws + off;
        off = (off + bytes + 255) & ~(size_t)255;
        return p;
    };

    unsigned short* xb   = (unsigned short*)alloc((size_t)NTOK * DIM * 2);
    unsigned short* Wb   = (unsigned short*)alloc((size_t)QKVW * DIM * 2);
    float*          bc   = (float*)alloc(QKVW * 4);
    unsigned short* QKV  = (unsigned short*)alloc((size_t)NTOK * QKVW * 2);
    unsigned short* Vt   = (unsigned short*)alloc((size_t)DIM * NTOK * 2);
    float*          rss  = (float*)alloc(NTOK * 4);
    float*          part = (float*)alloc((size_t)4 * NTOK * DIM * 4);
    unsigned short* S    = (unsigned short*)alloc((size_t)NTOK * NTOK * 2);

    // converts
    f2b_kernel<<<(NTOK * DIM / 4 + 255) / 256, 256, 0, stream>>>(x, xb, NTOK * DIM / 4);
    f2b_kernel<<<(DIM * DIM / 4 + 255) / 256, 256, 0, stream>>>(Wq, Wb, DIM * DIM / 4);
    f2b_kernel<<<(DIM * DIM / 4 + 255) / 256, 256, 0, stream>>>(Wk, Wb + DIM * DIM, DIM * DIM / 4);
    f2b_kernel<<<(DIM * DIM / 4 + 255) / 256, 256, 0, stream>>>(Wv, Wb + 2 * DIM * DIM, DIM * DIM / 4);
    bias_concat<<<6, 256, 0, stream>>>(bq, bk, bv, bc);
    hipMemsetAsync(rss, 0, NTOK * 4, stream);

    // QKV = x @ Wb^T + bias   [8192 x 1536], K=512   (grid 6x64, CH=6)
    gemmx<0, 6><<<dim3(QKVW / 256, NTOK / 128), 256, 0, stream>>>(
        xb, DIM, Wb, DIM, DIM, QKV, QKVW, bc, nullptr);

    // Vt[d][j] from QKV's V block
    transpose_v<<<dim3(NTOK / 64, DIM / 64), 256, 0, stream>>>(QKV, Vt);

    // S = Q @ K^T  [8192 x 8192], K=512 ; rowss += per-row sumsq  (grid 32x64, CH=16)
    gemmx<1, 16><<<dim3(NTOK / 256, NTOK / 128), 256, 0, stream>>>(
        QKV, QKVW, QKV + DIM, QKVW, DIM, S, NTOK, nullptr, rss);

    // O partials = S @ Vt^T, split-K=4  [8192 x 512]  (grid 2x64x4, CH=2)
    gemmx<2, 2><<<dim3(DIM / 256, NTOK / 128, 4), 256, 0, stream>>>(
        S, NTOK, Vt, NTOK, NTOK / 4, part, DIM, nullptr, nullptr);

    // out = (p0+p1+p2+p3) * rsqrt(rowss)
    reduce_scale<<<NTOK * DIM / 4 / 256, 256, 0, stream>>>(part, rss, out);
}